// Round 1
// baseline (361.465 us; speedup 1.0000x reference)
//
#include <hip/hip_runtime.h>

typedef __bf16 bf16;
typedef __attribute__((ext_vector_type(8))) __bf16 bf16x8;
typedef __attribute__((ext_vector_type(4))) float f32x4;
typedef __attribute__((ext_vector_type(4))) short s16x4;

#define SEQ 2048
#define DM 1024
#define NH 16
#define HD 64
#define SCALE 0.125f

static __device__ __forceinline__ void gl_lds16(const bf16* g, bf16* l) {
  __builtin_amdgcn_global_load_lds(
      (const __attribute__((address_space(1))) void*)g,
      (__attribute__((address_space(3))) void*)l, 16, 0, 0);
}

static __device__ __forceinline__ f32x4 mfma16(bf16x8 a, bf16x8 b, f32x4 c) {
  return __builtin_amdgcn_mfma_f32_16x16x32_bf16(a, b, c, 0, 0, 0);
}

__global__ void cast_bf16_k(const float* __restrict__ in, bf16* __restrict__ out, int n4) {
  int i = blockIdx.x * 256 + threadIdx.x;
  if (i >= n4) return;
  f32x4 v = ((const f32x4*)in)[i];
  s16x4 o;
#pragma unroll
  for (int j = 0; j < 4; ++j) o[j] = __builtin_bit_cast(short, (bf16)v[j]);
  ((s16x4*)out)[i] = o;
}

__global__ void rope_table_k(float* __restrict__ tab) {
  int idx = blockIdx.x * 256 + threadIdx.x;  // SEQ*32 total
  int s = idx >> 5, j = idx & 31;
  float inv = powf(10000.0f, -(float)j * (1.0f / 32.0f));
  float f = (float)s * inv;
  tab[idx * 2] = cosf(f);
  tab[idx * 2 + 1] = sinf(f);
}

__global__ void rope_apply_k(bf16* __restrict__ q, bf16* __restrict__ k,
                             const float* __restrict__ tab) {
  int idx = blockIdx.x * 256 + threadIdx.x;  // BATCH*SEQ*NH*32 total
  int j = idx & 31;
  int h = (idx >> 5) & (NH - 1);
  int s = (idx >> 9) & (SEQ - 1);
  int b = idx >> 20;
  float c = tab[(s * 32 + j) * 2];
  float sn = tab[(s * 32 + j) * 2 + 1];
  size_t base = (size_t)(b * SEQ + s) * DM + h * HD + j;
  float q0 = (float)q[base], q1 = (float)q[base + 32];
  q[base] = (bf16)(q0 * c - q1 * sn);
  q[base + 32] = (bf16)(q1 * c + q0 * sn);
  float k0 = (float)k[base], k1 = (float)k[base + 32];
  k[base] = (bf16)(k0 * c - k1 * sn);
  k[base + 32] = (bf16)(k1 * c + k0 * sn);
}

// C = A(MxK) * B(NxK)^T.  MODE 0: bf16 row-major out. MODE 1: bf16 per-head
// transposed out (vt[b][h][d][s]). MODE 2: f32 row-major out.
template <int MODE>
__global__ __launch_bounds__(256)
void gemm_bt(const bf16* __restrict__ A, const bf16* __restrict__ B,
             void* __restrict__ C, int M, int N, int K) {
  __shared__ __attribute__((aligned(16))) bf16 As[128 * 32];
  __shared__ __attribute__((aligned(16))) bf16 Bs[128 * 32];
  const int t = threadIdx.x;
  const int wv = t >> 6, ln = t & 63, lr = ln & 15, lg = ln >> 4;
  const int wr = wv >> 1, wc = wv & 1;
  const int m0 = blockIdx.y * 128, n0 = blockIdx.x * 128;
  const int srow = t >> 2, sslot = t & 3;

  f32x4 acc[4][4] = {};

  for (int kt = 0; kt < K; kt += 32) {
#pragma unroll
    for (int c = 0; c < 2; ++c) {
      int row = srow + (c << 6);
      int lsl = sslot ^ (row & 3);  // inverse-swizzled global source (rule 21)
      gl_lds16(A + (size_t)(m0 + row) * K + kt + lsl * 8, As + c * 2048 + wv * 512);
      gl_lds16(B + (size_t)(n0 + row) * K + kt + lsl * 8, Bs + c * 2048 + wv * 512);
    }
    __syncthreads();
    bf16x8 af[4], bfr[4];
#pragma unroll
    for (int i = 0; i < 4; ++i) {
      int ra = wr * 64 + i * 16 + lr;
      af[i] = *(const bf16x8*)(As + ra * 32 + ((lg ^ (ra & 3)) << 3));
      int rb = wc * 64 + i * 16 + lr;
      bfr[i] = *(const bf16x8*)(Bs + rb * 32 + ((lg ^ (rb & 3)) << 3));
    }
#pragma unroll
    for (int i = 0; i < 4; ++i)
#pragma unroll
      for (int j = 0; j < 4; ++j)
        acc[i][j] = mfma16(af[i], bfr[j], acc[i][j]);
    __syncthreads();
  }

#pragma unroll
  for (int i = 0; i < 4; ++i) {
    int row0 = m0 + wr * 64 + i * 16 + lg * 4;
#pragma unroll
    for (int j = 0; j < 4; ++j) {
      int col = n0 + wc * 64 + j * 16 + lr;
      if (MODE == 0) {
        bf16* Cb = (bf16*)C;
#pragma unroll
        for (int r = 0; r < 4; ++r)
          Cb[(size_t)(row0 + r) * N + col] = (bf16)acc[i][j][r];
      } else if (MODE == 1) {
        bf16* Cb = (bf16*)C;
        int h = col >> 6, d = col & 63;
        int b = row0 >> 11, s = row0 & (SEQ - 1);
        s16x4 pk;
#pragma unroll
        for (int r = 0; r < 4; ++r) pk[r] = __builtin_bit_cast(short, (bf16)acc[i][j][r]);
        *(s16x4*)(Cb + ((size_t)(b * NH + h) * HD + d) * SEQ + s) = pk;
      } else {
        float* Cf = (float*)C;
#pragma unroll
        for (int r = 0; r < 4; ++r)
          Cf[(size_t)(row0 + r) * N + col] = acc[i][j][r];
      }
    }
  }
}

// Flash attention: grid (SEQ/64, NH, BATCH), 256 threads = 4 waves,
// wave wv owns q rows [64*bx + 16*wv, +16). Causal. KVBLK=32.
__global__ __launch_bounds__(256)
void attn_k(const bf16* __restrict__ q, const bf16* __restrict__ k,
            const bf16* __restrict__ vt, bf16* __restrict__ ao) {
  __shared__ __attribute__((aligned(16))) bf16 plds[4][512];  // 16x32 per wave
  const int t = threadIdx.x, wv = t >> 6, ln = t & 63, lr = ln & 15, lg = ln >> 4;
  const int h = blockIdx.y, b = blockIdx.z;
  const int qrow0 = blockIdx.x * 64 + wv * 16;
  const bf16* qp = q + (size_t)(b * SEQ) * DM + h * HD;
  const bf16* kp = k + (size_t)(b * SEQ) * DM + h * HD;
  const bf16* vp = vt + (size_t)(b * NH + h) * HD * SEQ;
  bf16* pl = plds[wv];

  bf16x8 qf[2];
  qf[0] = *(const bf16x8*)(qp + (size_t)(qrow0 + lr) * DM + lg * 8);
  qf[1] = *(const bf16x8*)(qp + (size_t)(qrow0 + lr) * DM + 32 + lg * 8);

  f32x4 acc[4] = {};
  float m[4], l[4];
#pragma unroll
  for (int r = 0; r < 4; ++r) { m[r] = -1e30f; l[r] = 0.0f; }

  const int kv_end = qrow0 + 16;
  for (int s0 = 0; s0 < kv_end; s0 += 32) {
    f32x4 sc[2] = {};
#pragma unroll
    for (int fi = 0; fi < 2; ++fi) {
      const bf16* kr = kp + (size_t)(s0 + fi * 16 + lr) * DM + lg * 8;
      sc[fi] = mfma16(qf[0], *(const bf16x8*)kr, sc[fi]);
      sc[fi] = mfma16(qf[1], *(const bf16x8*)(kr + 32), sc[fi]);
    }
    float rmax[4], p[2][4];
#pragma unroll
    for (int r = 0; r < 4; ++r) {
      int row = qrow0 + lg * 4 + r;
#pragma unroll
      for (int fi = 0; fi < 2; ++fi) {
        int col = s0 + fi * 16 + lr;
        sc[fi][r] = (col <= row) ? sc[fi][r] * SCALE : -1e30f;
      }
      rmax[r] = fmaxf(sc[0][r], sc[1][r]);
    }
#pragma unroll
    for (int msk = 1; msk < 16; msk <<= 1)
#pragma unroll
      for (int r = 0; r < 4; ++r)
        rmax[r] = fmaxf(rmax[r], __shfl_xor(rmax[r], msk));
    float alpha[4], rsum[4];
#pragma unroll
    for (int r = 0; r < 4; ++r) {
      float mn = fmaxf(m[r], rmax[r]);
      alpha[r] = __expf(m[r] - mn);
      m[r] = mn;
      p[0][r] = __expf(sc[0][r] - mn);
      p[1][r] = __expf(sc[1][r] - mn);
      rsum[r] = p[0][r] + p[1][r];
    }
#pragma unroll
    for (int msk = 1; msk < 16; msk <<= 1)
#pragma unroll
      for (int r = 0; r < 4; ++r)
        rsum[r] += __shfl_xor(rsum[r], msk);
#pragma unroll
    for (int r = 0; r < 4; ++r) l[r] = l[r] * alpha[r] + rsum[r];
#pragma unroll
    for (int d0 = 0; d0 < 4; ++d0)
#pragma unroll
      for (int r = 0; r < 4; ++r) acc[d0][r] *= alpha[r];

    // P (D-layout) -> LDS (swizzled) -> A-layout fragment
#pragma unroll
    for (int fi = 0; fi < 2; ++fi)
#pragma unroll
      for (int r = 0; r < 4; ++r) {
        int row = lg * 4 + r;
        int col = fi * 16 + lr;
        int slot = col >> 3, within = col & 7;
        pl[row * 32 + ((slot ^ (row & 3)) << 3) + within] = (bf16)p[fi][r];
      }
    asm volatile("s_waitcnt lgkmcnt(0)" ::: "memory");
    bf16x8 pa = *(const bf16x8*)(pl + lr * 32 + ((lg ^ (lr & 3)) << 3));
#pragma unroll
    for (int d0 = 0; d0 < 4; ++d0) {
      const bf16* vr = vp + (size_t)(d0 * 16 + lr) * SEQ + s0 + lg * 8;
      acc[d0] = mfma16(pa, *(const bf16x8*)vr, acc[d0]);
    }
  }

  bf16* aop = ao + (size_t)(b * SEQ) * DM + h * HD;
#pragma unroll
  for (int d0 = 0; d0 < 4; ++d0)
#pragma unroll
    for (int r = 0; r < 4; ++r) {
      float o = acc[d0][r] / l[r];
      aop[(size_t)(qrow0 + lg * 4 + r) * DM + d0 * 16 + lr] = (bf16)o;
    }
}

extern "C" void kernel_launch(void* const* d_in, const int* in_sizes, int n_in,
                              void* d_out, int out_size, void* d_ws, size_t ws_size,
                              hipStream_t stream) {
  const float* x = (const float*)d_in[0];
  const float* wq = (const float*)d_in[1];
  const float* wk = (const float*)d_in[2];
  const float* wv = (const float*)d_in[3];
  const float* wo = (const float*)d_in[4];
  // d_in[5] = attention_mask: known causal tril, handled analytically.

  char* ws = (char*)d_ws;
  const size_t MB = 1ull << 20;
  bf16* xb  = (bf16*)ws;             // 8 MB (reused as attn-out after x is dead)
  bf16* wqb = (bf16*)(ws + 8 * MB);
  bf16* wkb = (bf16*)(ws + 10 * MB);
  bf16* wvb = (bf16*)(ws + 12 * MB);
  bf16* wob = (bf16*)(ws + 14 * MB);
  bf16* qb  = (bf16*)(ws + 16 * MB); // 8 MB
  bf16* kb  = (bf16*)(ws + 24 * MB); // 8 MB
  bf16* vtb = (bf16*)(ws + 32 * MB); // 8 MB
  float* tab = (float*)(ws + 40 * MB); // 512 KB
  bf16* aob = xb;

  cast_bf16_k<<<4096, 256, 0, stream>>>(x, xb, 1048576);
  cast_bf16_k<<<1024, 256, 0, stream>>>(wq, wqb, 262144);
  cast_bf16_k<<<1024, 256, 0, stream>>>(wk, wkb, 262144);
  cast_bf16_k<<<1024, 256, 0, stream>>>(wv, wvb, 262144);
  cast_bf16_k<<<1024, 256, 0, stream>>>(wo, wob, 262144);
  rope_table_k<<<256, 256, 0, stream>>>(tab);

  dim3 gg(8, 32);
  gemm_bt<0><<<gg, 256, 0, stream>>>(xb, wqb, qb, 4096, 1024, 1024);
  gemm_bt<0><<<gg, 256, 0, stream>>>(xb, wkb, kb, 4096, 1024, 1024);
  gemm_bt<1><<<gg, 256, 0, stream>>>(xb, wvb, vtb, 4096, 1024, 1024);

  rope_apply_k<<<8192, 256, 0, stream>>>(qb, kb, tab);

  attn_k<<<dim3(32, NH, 2), 256, 0, stream>>>(qb, kb, vtb, aob);

  gemm_bt<2><<<gg, 256, 0, stream>>>(aob, wob, d_out, 4096, 1024, 1024);
}

// Round 2
// 192.073 us; speedup vs baseline: 1.8819x; 1.8819x over previous
//
#include <hip/hip_runtime.h>

typedef __bf16 bf16;
typedef __attribute__((ext_vector_type(8))) __bf16 bf16x8;
typedef __attribute__((ext_vector_type(4))) float f32x4;
typedef __attribute__((ext_vector_type(4))) short s16x4;

#define SEQ 2048
#define DM 1024
#define NH 16
#define HD 64
// SCALE * log2(e) folded into q at projection epilogue; softmax uses exp2.
#define QSCALE 0.1803368801111204f

static __device__ __forceinline__ void gl_lds16(const bf16* g, bf16* l) {
  __builtin_amdgcn_global_load_lds(
      (const __attribute__((address_space(1))) void*)g,
      (__attribute__((address_space(3))) void*)l, 16, 0, 0);
}

static __device__ __forceinline__ f32x4 mfma16(bf16x8 a, bf16x8 b, f32x4 c) {
  return __builtin_amdgcn_mfma_f32_16x16x32_bf16(a, b, c, 0, 0, 0);
}

__global__ void cast_bf16_k(const float* __restrict__ in, bf16* __restrict__ out, int n4) {
  int i = blockIdx.x * 256 + threadIdx.x;
  if (i >= n4) return;
  f32x4 v = ((const f32x4*)in)[i];
  s16x4 o;
#pragma unroll
  for (int j = 0; j < 4; ++j) o[j] = __builtin_bit_cast(short, (bf16)v[j]);
  ((s16x4*)out)[i] = o;
}

__global__ void rope_table_k(float* __restrict__ tab) {
  int idx = blockIdx.x * 256 + threadIdx.x;  // SEQ*32 total
  int s = idx >> 5, j = idx & 31;
  float inv = powf(10000.0f, -(float)j * (1.0f / 32.0f));
  float f = (float)s * inv;
  tab[idx * 2] = cosf(f);
  tab[idx * 2 + 1] = sinf(f);
}

// Fused QKV projection: A = x [4096x1024] bf16, B = wqkv [3072x1024] bf16.
// n in [0,1024): q -> RoPE + QSCALE -> qh[b][h][s][64]
// n in [1024,2048): k -> RoPE -> kh[b][h][s][64]
// n in [2048,3072): v -> vt[b][h][d][s]
__global__ __launch_bounds__(256)
void gemm_qkv(const bf16* __restrict__ A, const bf16* __restrict__ B,
              bf16* __restrict__ qh, bf16* __restrict__ kh, bf16* __restrict__ vt,
              const float2* __restrict__ tab) {
  const int K = 1024;
  __shared__ __attribute__((aligned(16))) bf16 As[128 * 32];
  __shared__ __attribute__((aligned(16))) bf16 Bs[128 * 32];
  const int t = threadIdx.x;
  const int wv = t >> 6, ln = t & 63, lr = ln & 15, lg = ln >> 4;
  const int wr = wv >> 1, wc = wv & 1;
  const int m0 = blockIdx.y * 128, n0 = blockIdx.x * 128;
  const int srow = t >> 2, sslot = t & 3;
  const int seg = n0 >> 10;                       // 0=q 1=k 2=v (uniform per block)
  const int hh = ((n0 & 1023) + wc * 64) >> 6;    // head (uniform per wave)

  f32x4 acc[4][4] = {};

  for (int kt = 0; kt < K; kt += 32) {
#pragma unroll
    for (int c = 0; c < 2; ++c) {
      int row = srow + (c << 6);
      int lsl = sslot ^ (row & 3);
      gl_lds16(A + (size_t)(m0 + row) * K + kt + lsl * 8, As + c * 2048 + wv * 512);
      gl_lds16(B + (size_t)(n0 + row) * K + kt + lsl * 8, Bs + c * 2048 + wv * 512);
    }
    __syncthreads();
    bf16x8 af[4], bfr[4];
#pragma unroll
    for (int i = 0; i < 4; ++i) {
      int ra = wr * 64 + i * 16 + lr;
      af[i] = *(const bf16x8*)(As + ra * 32 + ((lg ^ (ra & 3)) << 3));
      int rb = wc * 64 + i * 16 + lr;
      bfr[i] = *(const bf16x8*)(Bs + rb * 32 + ((lg ^ (rb & 3)) << 3));
    }
#pragma unroll
    for (int i = 0; i < 4; ++i)
#pragma unroll
      for (int j = 0; j < 4; ++j)
        acc[i][j] = mfma16(af[i], bfr[j], acc[i][j]);
    __syncthreads();
  }

#pragma unroll
  for (int i = 0; i < 4; ++i) {
    int row0 = m0 + wr * 64 + i * 16 + lg * 4;
    int bb = row0 >> 11, s0r = row0 & (SEQ - 1);
    if (seg < 2) {
      bf16* dst = (seg == 0) ? qh : kh;
      float scl = (seg == 0) ? QSCALE : 1.0f;
      size_t base = ((size_t)(bb * NH + hh) * SEQ + s0r) * HD;
#pragma unroll
      for (int j = 0; j < 2; ++j) {
        int dlo = j * 16 + lr;  // 0..31
#pragma unroll
        for (int r = 0; r < 4; ++r) {
          float2 cs = tab[(size_t)(s0r + r) * 32 + dlo];
          float a = acc[i][j][r], b2 = acc[i][j + 2][r];
          float na = (a * cs.x - b2 * cs.y) * scl;
          float nb = (b2 * cs.x + a * cs.y) * scl;
          dst[base + (size_t)r * HD + dlo] = (bf16)na;
          dst[base + (size_t)r * HD + dlo + 32] = (bf16)nb;
        }
      }
    } else {
#pragma unroll
      for (int j = 0; j < 4; ++j) {
        int d = j * 16 + lr;
        s16x4 pk;
#pragma unroll
        for (int r = 0; r < 4; ++r) pk[r] = __builtin_bit_cast(short, (bf16)acc[i][j][r]);
        *(s16x4*)(vt + ((size_t)(bb * NH + hh) * HD + d) * SEQ + s0r) = pk;
      }
    }
  }
}

// C = A(MxK) * B(NxK)^T, f32 out (final projection)
__global__ __launch_bounds__(256)
void gemm_bt_f32(const bf16* __restrict__ A, const bf16* __restrict__ B,
                 float* __restrict__ C, int M, int N, int K) {
  __shared__ __attribute__((aligned(16))) bf16 As[128 * 32];
  __shared__ __attribute__((aligned(16))) bf16 Bs[128 * 32];
  const int t = threadIdx.x;
  const int wv = t >> 6, ln = t & 63, lr = ln & 15, lg = ln >> 4;
  const int wr = wv >> 1, wc = wv & 1;
  const int m0 = blockIdx.y * 128, n0 = blockIdx.x * 128;
  const int srow = t >> 2, sslot = t & 3;

  f32x4 acc[4][4] = {};

  for (int kt = 0; kt < K; kt += 32) {
#pragma unroll
    for (int c = 0; c < 2; ++c) {
      int row = srow + (c << 6);
      int lsl = sslot ^ (row & 3);
      gl_lds16(A + (size_t)(m0 + row) * K + kt + lsl * 8, As + c * 2048 + wv * 512);
      gl_lds16(B + (size_t)(n0 + row) * K + kt + lsl * 8, Bs + c * 2048 + wv * 512);
    }
    __syncthreads();
    bf16x8 af[4], bfr[4];
#pragma unroll
    for (int i = 0; i < 4; ++i) {
      int ra = wr * 64 + i * 16 + lr;
      af[i] = *(const bf16x8*)(As + ra * 32 + ((lg ^ (ra & 3)) << 3));
      int rb = wc * 64 + i * 16 + lr;
      bfr[i] = *(const bf16x8*)(Bs + rb * 32 + ((lg ^ (rb & 3)) << 3));
    }
#pragma unroll
    for (int i = 0; i < 4; ++i)
#pragma unroll
      for (int j = 0; j < 4; ++j)
        acc[i][j] = mfma16(af[i], bfr[j], acc[i][j]);
    __syncthreads();
  }

#pragma unroll
  for (int i = 0; i < 4; ++i) {
    int row0 = m0 + wr * 64 + i * 16 + lg * 4;
#pragma unroll
    for (int j = 0; j < 4; ++j) {
      int col = n0 + wc * 64 + j * 16 + lr;
#pragma unroll
      for (int r = 0; r < 4; ++r)
        C[(size_t)(row0 + r) * N + col] = acc[i][j][r];
    }
  }
}

// ---------------- Flash attention ----------------
// grid: 1024 blocks (balance-swizzled to (bx,h,b)), 256 thr = 4 waves.
// Block handles 64 q rows [bx*64,+64); wave wv owns 16 rows. KVBLK=64.
// LDS: K/V tiles double-buffered (swizzled), per-wave P transpose buffer.
__shared__ __attribute__((aligned(16))) bf16 attn_lds[1];  // (placeholder; real decls in kernel)

template <bool MASKED>
static __device__ __forceinline__ void attn_step(
    const bf16* __restrict__ Ksb, const bf16* __restrict__ Vsb, bf16* __restrict__ pl,
    const bf16x8* qf, f32x4* acc, float* m, float* l,
    int lr, int lg, int qrow0, int s0) {
  f32x4 sc[4] = {};
#pragma unroll
  for (int fi = 0; fi < 4; ++fi) {
    int row = fi * 16 + lr;
    int swz = row & 7;
#pragma unroll
    for (int c = 0; c < 2; ++c) {
      bf16x8 kf = *(const bf16x8*)(Ksb + row * 64 + (((c * 4 + lg) ^ swz) << 3));
      sc[fi] = mfma16(qf[c], kf, sc[fi]);
    }
  }
  float rmax[4];
#pragma unroll
  for (int r = 0; r < 4; ++r) {
    if (MASKED) {
      int row = qrow0 + lg * 4 + r;
#pragma unroll
      for (int fi = 0; fi < 4; ++fi) {
        int col = s0 + fi * 16 + lr;
        sc[fi][r] = (col <= row) ? sc[fi][r] : -3e38f;
      }
    }
    rmax[r] = fmaxf(fmaxf(sc[0][r], sc[1][r]), fmaxf(sc[2][r], sc[3][r]));
  }
#pragma unroll
  for (int msk = 1; msk < 16; msk <<= 1)
#pragma unroll
    for (int r = 0; r < 4; ++r)
      rmax[r] = fmaxf(rmax[r], __shfl_xor(rmax[r], msk));
  float alpha[4], rsum[4], p[4][4];
#pragma unroll
  for (int r = 0; r < 4; ++r) {
    float mn = fmaxf(m[r], rmax[r]);
    alpha[r] = exp2f(m[r] - mn);
    m[r] = mn;
#pragma unroll
    for (int fi = 0; fi < 4; ++fi) p[fi][r] = exp2f(sc[fi][r] - mn);
    rsum[r] = (p[0][r] + p[1][r]) + (p[2][r] + p[3][r]);
  }
#pragma unroll
  for (int msk = 1; msk < 16; msk <<= 1)
#pragma unroll
    for (int r = 0; r < 4; ++r)
      rsum[r] += __shfl_xor(rsum[r], msk);
#pragma unroll
  for (int r = 0; r < 4; ++r) l[r] = l[r] * alpha[r] + rsum[r];
#pragma unroll
  for (int d0 = 0; d0 < 4; ++d0)
#pragma unroll
    for (int r = 0; r < 4; ++r) acc[d0][r] *= alpha[r];

  // P (D-layout 16x64) -> per-wave LDS (swizzled) -> A-layout fragments
#pragma unroll
  for (int fi = 0; fi < 4; ++fi)
#pragma unroll
    for (int r = 0; r < 4; ++r) {
      int row = lg * 4 + r;
      int slot = fi * 2 + (lr >> 3);
      pl[row * 64 + (((slot) ^ (row & 7)) << 3) + (lr & 7)] = (bf16)p[fi][r];
    }
  asm volatile("s_waitcnt lgkmcnt(0)" ::: "memory");
  __builtin_amdgcn_sched_barrier(0);
#pragma unroll
  for (int kc = 0; kc < 2; ++kc) {
    bf16x8 pa = *(const bf16x8*)(pl + lr * 64 + (((kc * 4 + lg) ^ (lr & 7)) << 3));
#pragma unroll
    for (int d0 = 0; d0 < 4; ++d0) {
      int vrow = d0 * 16 + lr;
      bf16x8 vf = *(const bf16x8*)(Vsb + vrow * 64 + (((kc * 4 + lg) ^ (vrow & 7)) << 3));
      acc[d0] = mfma16(pa, vf, acc[d0]);
    }
  }
}

__global__ __launch_bounds__(256)
void attn_k(const bf16* __restrict__ qh, const bf16* __restrict__ kh,
            const bf16* __restrict__ vt, bf16* __restrict__ ao) {
  __shared__ __attribute__((aligned(16))) bf16 Ks[2][64 * 64];   // 16 KB
  __shared__ __attribute__((aligned(16))) bf16 Vs[2][64 * 64];   // 16 KB
  __shared__ __attribute__((aligned(16))) bf16 plds[4][16 * 64]; // 8 KB

  const int t = threadIdx.x, wv = t >> 6, ln = t & 63, lr = ln & 15, lg = ln >> 4;
  // trip-balance permutation of the 1024-block grid
  int lin = blockIdx.x + 32 * blockIdx.y + 512 * blockIdx.z;
  const int bx = (lin + ((lin >> 8) << 3)) & 31;
  const int h = (lin >> 5) & 15;
  const int b = (lin >> 9) & 1;

  const bf16* qp = qh + (size_t)(b * NH + h) * SEQ * HD;
  const bf16* kp = kh + (size_t)(b * NH + h) * SEQ * HD;
  const bf16* vp = vt + (size_t)(b * NH + h) * HD * SEQ;

  const int qrow0 = bx * 64 + wv * 16;
  const int nt = bx + 1;

  bf16x8 qf[2];
  qf[0] = *(const bf16x8*)(qp + (size_t)(qrow0 + lr) * HD + lg * 8);
  qf[1] = *(const bf16x8*)(qp + (size_t)(qrow0 + lr) * HD + 32 + lg * 8);

  f32x4 acc[4] = {};
  float m[4], l[4];
#pragma unroll
  for (int r = 0; r < 4; ++r) { m[r] = -3e38f; l[r] = 0.0f; }

  const int srow_base = wv * 16;   // wave stages rows [wv*16, +16) of each tile
  const int slot = ln & 7;
  const int rsub = ln >> 3;        // 0..7

  // stage tile `ti` into buffer `buf`
  auto STAGE = [&](int buf, int ti) {
    int s0 = ti * 64;
#pragma unroll
    for (int c = 0; c < 2; ++c) {
      int row = srow_base + c * 8 + rsub;
      int sl = slot ^ (row & 7);
      gl_lds16(kp + (size_t)(s0 + row) * HD + (sl << 3),
               &Ks[buf][0] + row * 64 - (size_t)(ln << 3));  // base must be wave-uniform
      gl_lds16(vp + (size_t)row * SEQ + s0 + (sl << 3),
               &Vs[buf][0] + row * 64 - (size_t)(ln << 3));
    }
  };
  // NOTE on the LDS base arithmetic above: global_load_lds writes to
  // (base + lane*16B). We want lane ln to land at byte (row*128 + ln%8*16)
  // with row = srow_base + c*8 + ln/8 -> base byte = (srow_base + c*8)*128,
  // uniform across the wave. Express that directly:
  (void)rsub;

  auto STAGE_U = [&](int buf, int ti) {
    int s0 = ti * 64;
#pragma unroll
    for (int c = 0; c < 2; ++c) {
      int row = srow_base + c * 8 + rsub;
      int sl = slot ^ (row & 7);
      bf16* kb_dst = &Ks[buf][0] + (srow_base + c * 8) * 64;  // wave-uniform
      bf16* vb_dst = &Vs[buf][0] + (srow_base + c * 8) * 64;
      gl_lds16(kp + (size_t)(s0 + row) * HD + (sl << 3), kb_dst);
      gl_lds16(vp + (size_t)row * SEQ + s0 + (sl << 3), vb_dst);
    }
  };

  STAGE_U(0, 0);
  asm volatile("s_waitcnt vmcnt(0)" ::: "memory");
  __builtin_amdgcn_s_barrier();

  int cur = 0;
  for (int ti = 0; ti < nt - 1; ++ti) {
    STAGE_U(cur ^ 1, ti + 1);
    attn_step<false>(&Ks[cur][0], &Vs[cur][0], &plds[wv][0], qf, acc, m, l, lr, lg, qrow0, ti * 64);
    asm volatile("s_waitcnt vmcnt(0)" ::: "memory");
    __builtin_amdgcn_s_barrier();
    cur ^= 1;
  }
  attn_step<true>(&Ks[cur][0], &Vs[cur][0], &plds[wv][0], qf, acc, m, l, lr, lg, qrow0, (nt - 1) * 64);

  bf16* aop = ao + (size_t)(b * SEQ) * DM + h * HD;
  float invl[4];
#pragma unroll
  for (int r = 0; r < 4; ++r) invl[r] = 1.0f / l[r];
#pragma unroll
  for (int d0 = 0; d0 < 4; ++d0)
#pragma unroll
    for (int r = 0; r < 4; ++r) {
      float o = acc[d0][r] * invl[r];
      aop[(size_t)(qrow0 + lg * 4 + r) * DM + d0 * 16 + lr] = (bf16)o;
    }
}

extern "C" void kernel_launch(void* const* d_in, const int* in_sizes, int n_in,
                              void* d_out, int out_size, void* d_ws, size_t ws_size,
                              hipStream_t stream) {
  const float* x = (const float*)d_in[0];
  const float* wq = (const float*)d_in[1];
  const float* wk = (const float*)d_in[2];
  const float* wv = (const float*)d_in[3];
  const float* wo = (const float*)d_in[4];
  // d_in[5] = attention_mask: known causal tril, handled analytically.

  char* ws = (char*)d_ws;
  const size_t MB = 1ull << 20;
  bf16* xb    = (bf16*)ws;              // 8 MB (reused as attn-out once x is dead)
  bf16* wqkvb = (bf16*)(ws + 8 * MB);   // 6 MB [3072][1024]
  bf16* wob   = (bf16*)(ws + 14 * MB);  // 2 MB
  bf16* qhb   = (bf16*)(ws + 16 * MB);  // 8 MB [b][h][s][64]
  bf16* khb   = (bf16*)(ws + 24 * MB);  // 8 MB [b][h][s][64]
  bf16* vtb   = (bf16*)(ws + 32 * MB);  // 8 MB [b][h][d][s]
  float* tab  = (float*)(ws + 40 * MB); // 512 KB float2[2048][32]
  bf16* aob = xb;

  cast_bf16_k<<<4096, 256, 0, stream>>>(x, xb, 1048576);
  cast_bf16_k<<<1024, 256, 0, stream>>>(wq, wqkvb, 262144);
  cast_bf16_k<<<1024, 256, 0, stream>>>(wk, wqkvb + 1024 * 1024, 262144);
  cast_bf16_k<<<1024, 256, 0, stream>>>(wv, wqkvb + 2048 * 1024, 262144);
  cast_bf16_k<<<1024, 256, 0, stream>>>(wo, wob, 262144);
  rope_table_k<<<256, 256, 0, stream>>>(tab);

  gemm_qkv<<<dim3(24, 32), 256, 0, stream>>>(xb, wqkvb, qhb, khb, vtb, (const float2*)tab);

  attn_k<<<dim3(32, NH, 2), 256, 0, stream>>>(qhb, khb, vtb, aob);

  gemm_bt_f32<<<dim3(8, 32), 256, 0, stream>>>(aob, wob, (float*)d_out, 4096, 1024, 1024);
}